// Round 4
// baseline (168.610 us; speedup 1.0000x reference)
//
#include <hip/hip_runtime.h>
#include <math.h>

#define NC 15
#define TOPKK 15
#define BG_F 15.0f
#define MAXC 256

// All-register rotated-box IoU. Mirrors pairwise_riou exactly:
// fixed candidate slots 0..15 = edge intersections (e1*4+e2),
// 16..19 = corners of box1, 20..23 = corners of box2; a validity BITMASK
// replaces boolean arrays; stable repeated min-extraction over angles
// (strict <, lowest slot first) replicates stable jnp.argsort order.
// No runtime array indexing anywhere -> no scratch.
__device__ __forceinline__ float obb_iou_reg(
    float cx1, float cy1, float w1, float h1, float a1,
    float cx2, float cy2, float w2, float h2, float a2) {
  const float dxs[4] = {0.5f, 0.5f, -0.5f, -0.5f};
  const float dys[4] = {-0.5f, 0.5f, 0.5f, -0.5f};
  float c1 = cosf(a1), s1 = sinf(a1), c2 = cosf(a2), s2 = sinf(a2);
  float ax[4], ay[4], bx[4], by[4];
#pragma unroll
  for (int k = 0; k < 4; k++) {
    float dx = dxs[k] * w1, dy = dys[k] * h1;
    ax[k] = cx1 + dx * c1 - dy * s1;
    ay[k] = cy1 + dx * s1 + dy * c1;
    dx = dxs[k] * w2; dy = dys[k] * h2;
    bx[k] = cx2 + dx * c2 - dy * s2;
    by[k] = cy2 + dx * s2 + dy * c2;
  }
  float qx[24], qy[24];
#pragma unroll
  for (int k = 0; k < 24; k++) { qx[k] = 0.f; qy[k] = 0.f; }
  unsigned valid = 0u;
  // slots 0..15: edge-edge intersections
#pragma unroll
  for (int e1 = 0; e1 < 4; e1++) {
    float d1x = ax[(e1 + 1) & 3] - ax[e1], d1y = ay[(e1 + 1) & 3] - ay[e1];
#pragma unroll
    for (int e2 = 0; e2 < 4; e2++) {
      float d2x = bx[(e2 + 1) & 3] - bx[e2], d2y = by[(e2 + 1) & 3] - by[e2];
      float den = d1x * d2y - d1y * d2x;
      float qpx = bx[e2] - ax[e1], qpy = by[e2] - ay[e1];
      float t = (qpx * d2y - qpy * d2x) / den;
      float u = (qpx * d1y - qpy * d1x) / den;
      bool ok = (fabsf(den) > 1e-10f) &&
                (t >= 0.f) && (t <= 1.f) && (u >= 0.f) && (u <= 1.f);
      if (ok) {
        qx[e1 * 4 + e2] = ax[e1] + t * d1x;
        qy[e1 * 4 + e2] = ay[e1] + t * d1y;
        valid |= (1u << (e1 * 4 + e2));
      }
    }
  }
  const float eps = 1e-6f;
  // slots 16..19: corners of box1 inside box2
#pragma unroll
  for (int k = 0; k < 4; k++) {
    float rx = ax[k] - cx2, ry = ay[k] - cy2;
    float x = rx * c2 + ry * s2, y = -rx * s2 + ry * c2;
    if (fabsf(x) <= w2 * 0.5f + eps && fabsf(y) <= h2 * 0.5f + eps) {
      qx[16 + k] = ax[k]; qy[16 + k] = ay[k];
      valid |= (1u << (16 + k));
    }
  }
  // slots 20..23: corners of box2 inside box1
#pragma unroll
  for (int k = 0; k < 4; k++) {
    float rx = bx[k] - cx1, ry = by[k] - cy1;
    float x = rx * c1 + ry * s1, y = -rx * s1 + ry * c1;
    if (fabsf(x) <= w1 * 0.5f + eps && fabsf(y) <= h1 * 0.5f + eps) {
      qx[20 + k] = bx[k]; qy[20 + k] = by[k];
      valid |= (1u << (20 + k));
    }
  }
  int cnt = __popc(valid);
  float inter = 0.f;
  if (cnt > 0) {
    float sx = 0.f, sy = 0.f;
#pragma unroll
    for (int k = 0; k < 24; k++) {
      bool v = (valid >> k) & 1u;
      sx += v ? qx[k] : 0.f;
      sy += v ? qy[k] : 0.f;
    }
    float ccx = sx / (float)cnt, ccy = sy / (float)cnt;
    float ang[24];
#pragma unroll
    for (int k = 0; k < 24; k++) {
      float a = atan2f(qy[k] - ccy, qx[k] - ccx);
      ang[k] = ((valid >> k) & 1u) ? a : 1e9f;
    }
    // stable min-extraction = stable ascending sort; fan shoelace
    unsigned used = ~valid;  // invalid slots pre-consumed
    float area2 = 0.f;
    float prevx = 0.f, prevy = 0.f, firstx = 0.f, firsty = 0.f;
    for (int s = 0; s < cnt; s++) {
      float ba = 1e30f, bxv = 0.f, byv = 0.f;
      int bk = 0;
#pragma unroll
      for (int k = 0; k < 24; k++) {
        bool avail = !((used >> k) & 1u);
        bool better = avail && (ang[k] < ba);
        if (better) { ba = ang[k]; bxv = qx[k]; byv = qy[k]; bk = k; }
      }
      used |= (1u << bk);
      float vx = bxv - ccx, vy = byv - ccy;
      if (s == 0) { firstx = vx; firsty = vy; }
      else { area2 += prevx * vy - prevy * vx; }
      prevx = vx; prevy = vy;
    }
    area2 += prevx * firsty - prevy * firstx;  // closing edge back to first
    inter = 0.5f * fabsf(area2);
  }
  float areaA = w1 * h1, areaB = w2 * h2;
  return inter / fmaxf(areaA + areaB - inter, 1e-8f);
}

// Fused: per-gt centerness argmax (wave shfl reduce + 1 atomicMax/wave) +
// validity scan with wave-aggregated candidate append. Blocks with g==0 also
// zero point_key (replaces the big memset).
// Layout: blockIdx.x = g * BPG + i_chunk -> gtb loads wave-uniform,
// pts/rr/spp coalesced.
__global__ void k_scanc(const float* __restrict__ pts,
                        const float* __restrict__ rr,
                        const float* __restrict__ spp,
                        const float* __restrict__ gtb,
                        unsigned long long* __restrict__ cent_key,
                        int* __restrict__ cand_cnt,
                        int* __restrict__ cand_i,
                        unsigned long long* __restrict__ point_key,
                        int N, int G, int BPG) {
  int g = blockIdx.x / BPG;
  int i = (blockIdx.x % BPG) * blockDim.x + threadIdx.x;
  if (g == 0 && i < N) point_key[i] = 0ull;
  float gx = gtb[g * 5 + 0], gy = gtb[g * 5 + 1];
  float gw = gtb[g * 5 + 2], gh = gtb[g * 5 + 3], ga = gtb[g * 5 + 4];
  float cg = cosf(ga), sg = sinf(ga);
  unsigned long long key = 0ull;
  bool valid = false;
  if (i < N) {
    float px = pts[i * 2 + 0] - gx, py = pts[i * 2 + 1] - gy;
    float ox = px * cg + py * sg, oy = -px * sg + py * cg;
    float nx = 2.f * ox / gw, ny = 2.f * oy / gh;
    float ctn = fmaxf(1.f - sqrtf((nx * nx + ny * ny + 1e-8f) * 0.5f), 0.f);
    key = ((unsigned long long)__float_as_uint(ctn) << 32) |
          (unsigned long long)(0xFFFFFFFFu - (unsigned)i);
    float hw = gw * 0.5f, hh = gh * 0.5f;
    float l = hw + ox, tt = hh + oy, r = hw - ox, b = hh - oy;
    float minb = fminf(fminf(l, tt), fminf(r, b));
    float maxb = fmaxf(fmaxf(l, tt), fmaxf(r, b));
    float cr = 1.5f * spp[i];
    valid = (minb > 0.f) && (fabsf(ox) < cr) && (fabsf(oy) < cr) &&
            (maxb >= rr[i * 2 + 0]) && (maxb <= rr[i * 2 + 1]);
  }
  // wave-level centerness max (max key, min i on value ties)
  unsigned long long k2 = key;
#pragma unroll
  for (int o = 32; o > 0; o >>= 1) {
    unsigned long long other = __shfl_xor(k2, o, 64);
    if (other > k2) k2 = other;
  }
  int lane = threadIdx.x & 63;
  if (lane == 0) atomicMax(&cent_key[g], k2);
  // wave-aggregated append of valid point indices
  unsigned long long ball = __ballot(valid);
  if (ball) {
    int leader = __ffsll((unsigned long long)ball) - 1;
    int base = 0;
    if (lane == leader) base = atomicAdd(&cand_cnt[g], __popcll(ball));
    base = __shfl(base, leader, 64);
    if (valid) {
      int off = __popcll(ball & ((1ull << lane) - 1ull));
      int slot = base + off;
      if (slot < MAXC) cand_i[g * MAXC + slot] = i;
    }
  }
}

// Fused heavy phase + top-15: block = gt, tid = candidate slot.
// Per-thread cost (softmax + decode + register IoU), then 15 rounds of
// block argmax with key = (val_bits<<32)|~i (value desc, index asc = exact
// lax.top_k tie rule). All costs > 0 so rounds = min(15, cnt) implements the
// vals != 0 filter. Winners atomicMax the per-point area key
// (area_bits<<32)|(G-1-g) -> max area, min g on ties (jnp.argmax rule).
__global__ void k_iotop(const float* __restrict__ pts,
                        const float* __restrict__ spp,
                        const float* __restrict__ gtb,
                        const int* __restrict__ gtl,
                        const float* __restrict__ preds,
                        const float* __restrict__ probs,
                        const int* __restrict__ cand_cnt,
                        const int* __restrict__ cand_i,
                        unsigned long long* __restrict__ point_key,
                        int G) {
  int g = blockIdx.x;
  int tid = threadIdx.x;
  int lane = tid & 63, wid = tid >> 6;
  int cnt = cand_cnt[g];
  if (cnt > MAXC) cnt = MAXC;
  float gx = gtb[g * 5 + 0], gy = gtb[g * 5 + 1];
  float gw = gtb[g * 5 + 2], gh = gtb[g * 5 + 3], ga = gtb[g * 5 + 4];

  unsigned long long key = 0ull;
  if (tid < cnt) {
    int i = cand_i[g * MAXC + tid];
    float cg = cosf(ga), sg = sinf(ga);
    float ptx = pts[i * 2 + 0], pty = pts[i * 2 + 1];
    float px = ptx - gx, py = pty - gy;
    float ox = px * cg + py * sg, oy = -px * sg + py * cg;
    float nx = 2.f * ox / gw, ny = 2.f * oy / gh;
    float ctn = fmaxf(1.f - sqrtf((nx * nx + ny * ny + 1e-8f) * 0.5f), 0.f);

    // softmax prob of this gt's label (jax.nn.softmax with max subtraction)
    float pv[NC];
    float m = -1e30f;
#pragma unroll
    for (int k = 0; k < NC; k++) { pv[k] = probs[i * NC + k]; m = fmaxf(m, pv[k]); }
    float ss = 0.f;
#pragma unroll
    for (int k = 0; k < NC; k++) { pv[k] = expf(pv[k] - m); ss += pv[k]; }
    float prob = pv[gtl[g]] / ss;

    // decode det box (mirrors _decode with stride-scaled preds)
    float st = spp[i];
    float d0 = preds[i * 5 + 0] * st, d1 = preds[i * 5 + 1] * st;
    float d2 = preds[i * 5 + 2] * st, d3 = preds[i * 5 + 3] * st;
    float angp = preds[i * 5 + 4];
    float c = cosf(angp), s = sinf(angp);
    float w = d0 + d2, h = d1 + d3;
    float otx = (d2 - d0) * 0.5f, oty = (d3 - d1) * 0.5f;
    float dox = c * otx - s * oty, doy = s * otx + c * oty;
    const float PI = 3.14159265358979323846f;
    float a = fmodf(angp + PI * 0.5f, PI);
    if (a < 0.f) a += PI;
    a -= PI * 0.5f;

    float iou = obb_iou_reg(ptx + dox, pty + doy, w, h, a,
                            gx, gy, gw, gh, ga);
    float cval = 0.2f * ctn + 0.2f * iou + 0.6f * prob;
    key = ((unsigned long long)__float_as_uint(cval) << 32) |
          (unsigned long long)(0xFFFFFFFFu - (unsigned)i);
  }

  float area = gw * gh;
  unsigned long long area_key =
      (((unsigned long long)__float_as_uint(area)) << 32) |
      (unsigned long long)(unsigned)(G - 1 - g);
  __shared__ unsigned long long swin[4];
  int rounds = cnt < TOPKK ? cnt : TOPKK;
  for (int r = 0; r < rounds; r++) {
    unsigned long long k2 = key;
#pragma unroll
    for (int o = 32; o > 0; o >>= 1) {
      unsigned long long other = __shfl_xor(k2, o, 64);
      if (other > k2) k2 = other;
    }
    if (lane == 0) swin[wid] = k2;
    __syncthreads();
    unsigned long long w = swin[0];
#pragma unroll
    for (int q = 1; q < 4; q++) if (swin[q] > w) w = swin[q];
    __syncthreads();
    if (w == 0ull) break;
    if (key == w) key = 0ull;  // unique owner (i unique per gt) consumes
    if (tid == 0) {
      unsigned iwin = 0xFFFFFFFFu - (unsigned)(w & 0xFFFFFFFFull);
      atomicMax(&point_key[iwin], area_key);
    }
  }
}

// Per point: resolve key -> (ind, label), count matches, write bt/at.
__global__ void k_assign(const unsigned long long* __restrict__ point_key,
                         const float* __restrict__ pts,
                         const float* __restrict__ spp,
                         const float* __restrict__ gtb,
                         const int* __restrict__ gtl,
                         int* __restrict__ counts,
                         float* __restrict__ out_labels,
                         float* __restrict__ out_bt,
                         float* __restrict__ out_at,
                         int N, int G) {
  int i = blockIdx.x * blockDim.x + threadIdx.x;
  if (i >= N) return;
  unsigned long long key = point_key[i];
  int g = 0;
  if (key != 0ull) {
    g = (G - 1) - (int)(key & 0xFFFFFFFFull);
    out_labels[i] = (float)gtl[g];
    atomicAdd(&counts[g], 1);
  } else {
    out_labels[i] = BG_F;  // argmax of all-zero row -> ind 0, label BG
  }
  float gx = gtb[g * 5 + 0], gy = gtb[g * 5 + 1];
  float gw = gtb[g * 5 + 2], gh = gtb[g * 5 + 3], ga = gtb[g * 5 + 4];
  float cg = cosf(ga), sg = sinf(ga);
  float px = pts[i * 2 + 0] - gx, py = pts[i * 2 + 1] - gy;
  float ox = px * cg + py * sg, oy = -px * sg + py * cg;
  float st = spp[i];
  out_bt[i * 4 + 0] = (gw * 0.5f + ox) / st;
  out_bt[i * 4 + 1] = (gh * 0.5f + oy) / st;
  out_bt[i * 4 + 2] = (gw * 0.5f - ox) / st;
  out_bt[i * 4 + 3] = (gh * 0.5f - oy) / st;
  out_at[i] = ga;
}

// Serial: unmatched gts claim their anchor point (ascending g, overwrite =
// last wins, matching XLA scatter), rewriting that point's outputs.
__global__ void k_fix(const int* __restrict__ counts,
                      const unsigned long long* __restrict__ cent_key,
                      const float* __restrict__ pts,
                      const float* __restrict__ spp,
                      const float* __restrict__ gtb,
                      const int* __restrict__ gtl,
                      float* __restrict__ out_labels,
                      float* __restrict__ out_bt,
                      float* __restrict__ out_at,
                      int G) {
  if (blockIdx.x != 0 || threadIdx.x != 0) return;
  for (int g = 0; g < G; g++) {
    if (counts[g] == 0) {
      unsigned i = 0xFFFFFFFFu - (unsigned)(cent_key[g] & 0xFFFFFFFFull);
      out_labels[i] = (float)gtl[g];
      float gx = gtb[g * 5 + 0], gy = gtb[g * 5 + 1];
      float gw = gtb[g * 5 + 2], gh = gtb[g * 5 + 3], ga = gtb[g * 5 + 4];
      float cg = cosf(ga), sg = sinf(ga);
      float px = pts[i * 2 + 0] - gx, py = pts[i * 2 + 1] - gy;
      float ox = px * cg + py * sg, oy = -px * sg + py * cg;
      float st = spp[i];
      out_bt[i * 4 + 0] = (gw * 0.5f + ox) / st;
      out_bt[i * 4 + 1] = (gh * 0.5f + oy) / st;
      out_bt[i * 4 + 2] = (gw * 0.5f - ox) / st;
      out_bt[i * 4 + 3] = (gh * 0.5f - oy) / st;
      out_at[i] = ga;
    }
  }
}

extern "C" void kernel_launch(void* const* d_in, const int* in_sizes, int n_in,
                              void* d_out, int out_size, void* d_ws, size_t ws_size,
                              hipStream_t stream) {
  const float* pts   = (const float*)d_in[0];
  const float* rr    = (const float*)d_in[1];
  const float* spp   = (const float*)d_in[2];
  const float* gtb   = (const float*)d_in[3];
  const int*   gtl   = (const int*)d_in[4];
  const float* preds = (const float*)d_in[5];
  const float* probs = (const float*)d_in[6];
  int N = in_sizes[0] / 2;
  int G = in_sizes[3] / 5;

  float* out = (float*)d_out;
  float* out_labels = out;                   // N
  float* out_bt     = out + N;               // N*4
  float* out_at     = out + 5 * (size_t)N;   // N

  // workspace: [cent_key G u64 | cand_cnt G i32 | counts G i32] <- memset 0
  //            [point_key N u64 (zeroed by k_scanc g==0)] [cand_i G*MAXC i32]
  unsigned long long* cent_key  = (unsigned long long*)d_ws;   // G
  int* cand_cnt = (int*)(cent_key + G);                        // G
  int* counts   = cand_cnt + G;                                // G
  unsigned long long* point_key = (unsigned long long*)(counts + G);  // N
  int* cand_i   = (int*)(point_key + N);                       // G*MAXC

  size_t zbytes = (size_t)G * 8 + (size_t)G * 4 * 2;
  hipMemsetAsync(d_ws, 0, zbytes, stream);

  const int thr = 256;
  int BPG = (N + thr - 1) / thr;
  hipLaunchKernelGGL(k_scanc, dim3(G * BPG), dim3(thr), 0, stream,
                     pts, rr, spp, gtb, cent_key, cand_cnt, cand_i,
                     point_key, N, G, BPG);
  hipLaunchKernelGGL(k_iotop, dim3(G), dim3(MAXC), 0, stream,
                     pts, spp, gtb, gtl, preds, probs,
                     cand_cnt, cand_i, point_key, G);
  hipLaunchKernelGGL(k_assign, dim3((N + thr - 1) / thr), dim3(thr), 0, stream,
                     point_key, pts, spp, gtb, gtl, counts,
                     out_labels, out_bt, out_at, N, G);
  hipLaunchKernelGGL(k_fix, dim3(1), dim3(64), 0, stream,
                     counts, cent_key, pts, spp, gtb, gtl,
                     out_labels, out_bt, out_at, G);
}

// Round 5
// 130.790 us; speedup vs baseline: 1.2892x; 1.2892x over previous
//
#include <hip/hip_runtime.h>
#include <math.h>

#define NC 15
#define TOPKK 15
#define BG_F 15.0f
#define MAXC 256

// All-register rotated-box IoU. Mirrors pairwise_riou exactly:
// fixed candidate slots 0..15 = edge intersections (e1*4+e2),
// 16..19 = corners of box1, 20..23 = corners of box2; a validity BITMASK
// replaces boolean arrays; stable repeated min-extraction over angles
// (strict <, lowest slot first) replicates stable jnp.argsort order.
// No runtime array indexing anywhere -> no scratch.
__device__ __forceinline__ float obb_iou_reg(
    float cx1, float cy1, float w1, float h1, float a1,
    float cx2, float cy2, float w2, float h2, float a2) {
  const float dxs[4] = {0.5f, 0.5f, -0.5f, -0.5f};
  const float dys[4] = {-0.5f, 0.5f, 0.5f, -0.5f};
  float c1 = cosf(a1), s1 = sinf(a1), c2 = cosf(a2), s2 = sinf(a2);
  float ax[4], ay[4], bx[4], by[4];
#pragma unroll
  for (int k = 0; k < 4; k++) {
    float dx = dxs[k] * w1, dy = dys[k] * h1;
    ax[k] = cx1 + dx * c1 - dy * s1;
    ay[k] = cy1 + dx * s1 + dy * c1;
    dx = dxs[k] * w2; dy = dys[k] * h2;
    bx[k] = cx2 + dx * c2 - dy * s2;
    by[k] = cy2 + dx * s2 + dy * c2;
  }
  float qx[24], qy[24];
#pragma unroll
  for (int k = 0; k < 24; k++) { qx[k] = 0.f; qy[k] = 0.f; }
  unsigned valid = 0u;
#pragma unroll
  for (int e1 = 0; e1 < 4; e1++) {
    float d1x = ax[(e1 + 1) & 3] - ax[e1], d1y = ay[(e1 + 1) & 3] - ay[e1];
#pragma unroll
    for (int e2 = 0; e2 < 4; e2++) {
      float d2x = bx[(e2 + 1) & 3] - bx[e2], d2y = by[(e2 + 1) & 3] - by[e2];
      float den = d1x * d2y - d1y * d2x;
      float qpx = bx[e2] - ax[e1], qpy = by[e2] - ay[e1];
      float t = (qpx * d2y - qpy * d2x) / den;
      float u = (qpx * d1y - qpy * d1x) / den;
      bool ok = (fabsf(den) > 1e-10f) &&
                (t >= 0.f) && (t <= 1.f) && (u >= 0.f) && (u <= 1.f);
      if (ok) {
        qx[e1 * 4 + e2] = ax[e1] + t * d1x;
        qy[e1 * 4 + e2] = ay[e1] + t * d1y;
        valid |= (1u << (e1 * 4 + e2));
      }
    }
  }
  const float eps = 1e-6f;
#pragma unroll
  for (int k = 0; k < 4; k++) {
    float rx = ax[k] - cx2, ry = ay[k] - cy2;
    float x = rx * c2 + ry * s2, y = -rx * s2 + ry * c2;
    if (fabsf(x) <= w2 * 0.5f + eps && fabsf(y) <= h2 * 0.5f + eps) {
      qx[16 + k] = ax[k]; qy[16 + k] = ay[k];
      valid |= (1u << (16 + k));
    }
  }
#pragma unroll
  for (int k = 0; k < 4; k++) {
    float rx = bx[k] - cx1, ry = by[k] - cy1;
    float x = rx * c1 + ry * s1, y = -rx * s1 + ry * c1;
    if (fabsf(x) <= w1 * 0.5f + eps && fabsf(y) <= h1 * 0.5f + eps) {
      qx[20 + k] = bx[k]; qy[20 + k] = by[k];
      valid |= (1u << (20 + k));
    }
  }
  int cnt = __popc(valid);
  float inter = 0.f;
  if (cnt > 0) {
    float sx = 0.f, sy = 0.f;
#pragma unroll
    for (int k = 0; k < 24; k++) {
      bool v = (valid >> k) & 1u;
      sx += v ? qx[k] : 0.f;
      sy += v ? qy[k] : 0.f;
    }
    float ccx = sx / (float)cnt, ccy = sy / (float)cnt;
    float ang[24];
#pragma unroll
    for (int k = 0; k < 24; k++) {
      float a = atan2f(qy[k] - ccy, qx[k] - ccx);
      ang[k] = ((valid >> k) & 1u) ? a : 1e9f;
    }
    unsigned used = ~valid;  // invalid slots pre-consumed
    float area2 = 0.f;
    float prevx = 0.f, prevy = 0.f, firstx = 0.f, firsty = 0.f;
    for (int s = 0; s < cnt; s++) {
      float ba = 1e30f, bxv = 0.f, byv = 0.f;
      int bk = 0;
#pragma unroll
      for (int k = 0; k < 24; k++) {
        bool avail = !((used >> k) & 1u);
        bool better = avail && (ang[k] < ba);
        if (better) { ba = ang[k]; bxv = qx[k]; byv = qy[k]; bk = k; }
      }
      used |= (1u << bk);
      float vx = bxv - ccx, vy = byv - ccy;
      if (s == 0) { firstx = vx; firsty = vy; }
      else { area2 += prevx * vy - prevy * vx; }
      prevx = vx; prevy = vy;
    }
    area2 += prevx * firsty - prevy * firstx;  // closing edge
    inter = 0.5f * fabsf(area2);
  }
  float areaA = w1 * h1, areaB = w2 * h2;
  return inter / fmaxf(areaA + areaB - inter, 1e-8f);
}

// One block per gt: (1) stride-scan all points -> centerness argmax in
// registers (block reduce, PLAIN STORE to cent_key[g] -- no global atomics)
// + LDS candidate list of valid points; (2) per-candidate cost (softmax +
// decode + register IoU); (3) top-15 block argmax rounds with exact
// lax.top_k tie rule (value desc, index asc); winners atomicMax the
// per-point area key (area_bits<<32)|(G-1-g) -> max area, min g on ties.
__global__ void k_all(const float* __restrict__ pts,
                      const float* __restrict__ rr,
                      const float* __restrict__ spp,
                      const float* __restrict__ gtb,
                      const int* __restrict__ gtl,
                      const float* __restrict__ preds,
                      const float* __restrict__ probs,
                      unsigned long long* __restrict__ cent_key,
                      unsigned long long* __restrict__ point_key,
                      int N, int G) {
  int g = blockIdx.x;
  int tid = threadIdx.x;
  int lane = tid & 63, wid = tid >> 6;
  float gx = gtb[g * 5 + 0], gy = gtb[g * 5 + 1];
  float gw = gtb[g * 5 + 2], gh = gtb[g * 5 + 3], ga = gtb[g * 5 + 4];
  float cg = cosf(ga), sg = sinf(ga);
  float inv_gw = 2.f / gw, inv_gh = 2.f / gh;
  float hw = gw * 0.5f, hh = gh * 0.5f;

  __shared__ int s_cnt;
  __shared__ int s_ci[MAXC];
  __shared__ unsigned long long swin[4];
  if (tid == 0) s_cnt = 0;
  __syncthreads();

  const float2* pts2 = (const float2*)pts;
  const float2* rr2 = (const float2*)rr;
  unsigned long long best = 0ull;
  for (int i = tid; i < N; i += 256) {
    float2 p = pts2[i];
    float px = p.x - gx, py = p.y - gy;
    float ox = px * cg + py * sg, oy = -px * sg + py * cg;
    float nx = ox * inv_gw, ny = oy * inv_gh;
    float ctn = fmaxf(1.f - sqrtf((nx * nx + ny * ny + 1e-8f) * 0.5f), 0.f);
    unsigned long long key =
        ((unsigned long long)__float_as_uint(ctn) << 32) |
        (unsigned long long)(0xFFFFFFFFu - (unsigned)i);
    if (key > best) best = key;  // max ctn, min i on ties (~i order)
    float l = hw + ox, tt = hh + oy, r = hw - ox, b = hh - oy;
    float minb = fminf(fminf(l, tt), fminf(r, b));
    float maxb = fmaxf(fmaxf(l, tt), fmaxf(r, b));
    float cr = 1.5f * spp[i];
    float2 rv = rr2[i];
    bool valid = (minb > 0.f) && (fabsf(ox) < cr) && (fabsf(oy) < cr) &&
                 (maxb >= rv.x) && (maxb <= rv.y);
    if (valid) {
      int slot = atomicAdd(&s_cnt, 1);
      if (slot < MAXC) s_ci[slot] = i;
    }
  }
  // block reduce centerness key: wave shfl + 4-entry LDS combine
#pragma unroll
  for (int o = 32; o > 0; o >>= 1) {
    unsigned long long other = __shfl_xor(best, o, 64);
    if (other > best) best = other;
  }
  if (lane == 0) swin[wid] = best;
  __syncthreads();
  if (tid == 0) {
    unsigned long long m = swin[0];
#pragma unroll
    for (int q = 1; q < 4; q++) if (swin[q] > m) m = swin[q];
    cent_key[g] = m;
  }
  __syncthreads();
  int cnt = s_cnt;
  if (cnt > MAXC) cnt = MAXC;

  // heavy phase: cost per candidate
  unsigned long long key = 0ull;
  if (tid < cnt) {
    int i = s_ci[tid];
    float ptx = pts[i * 2 + 0], pty = pts[i * 2 + 1];
    float px = ptx - gx, py = pty - gy;
    float ox = px * cg + py * sg, oy = -px * sg + py * cg;
    float nx = ox * inv_gw, ny = oy * inv_gh;
    float ctn = fmaxf(1.f - sqrtf((nx * nx + ny * ny + 1e-8f) * 0.5f), 0.f);

    // softmax prob of this gt's label (jax.nn.softmax with max subtraction)
    float pv[NC];
    float m = -1e30f;
#pragma unroll
    for (int k = 0; k < NC; k++) { pv[k] = probs[i * NC + k]; m = fmaxf(m, pv[k]); }
    float ss = 0.f;
#pragma unroll
    for (int k = 0; k < NC; k++) { pv[k] = expf(pv[k] - m); ss += pv[k]; }
    float prob = pv[gtl[g]] / ss;

    // decode det box (mirrors _decode with stride-scaled preds)
    float st = spp[i];
    float d0 = preds[i * 5 + 0] * st, d1 = preds[i * 5 + 1] * st;
    float d2 = preds[i * 5 + 2] * st, d3 = preds[i * 5 + 3] * st;
    float angp = preds[i * 5 + 4];
    float c = cosf(angp), s = sinf(angp);
    float w = d0 + d2, h = d1 + d3;
    float otx = (d2 - d0) * 0.5f, oty = (d3 - d1) * 0.5f;
    float dox = c * otx - s * oty, doy = s * otx + c * oty;
    const float PI = 3.14159265358979323846f;
    float a = fmodf(angp + PI * 0.5f, PI);
    if (a < 0.f) a += PI;
    a -= PI * 0.5f;

    float iou = obb_iou_reg(ptx + dox, pty + doy, w, h, a,
                            gx, gy, gw, gh, ga);
    float cval = 0.2f * ctn + 0.2f * iou + 0.6f * prob;
    key = ((unsigned long long)__float_as_uint(cval) << 32) |
          (unsigned long long)(0xFFFFFFFFu - (unsigned)i);
  }

  float area = gw * gh;
  unsigned long long area_key =
      (((unsigned long long)__float_as_uint(area)) << 32) |
      (unsigned long long)(unsigned)(G - 1 - g);
  int rounds = cnt < TOPKK ? cnt : TOPKK;
  for (int r = 0; r < rounds; r++) {
    unsigned long long k2 = key;
#pragma unroll
    for (int o = 32; o > 0; o >>= 1) {
      unsigned long long other = __shfl_xor(k2, o, 64);
      if (other > k2) k2 = other;
    }
    if (lane == 0) swin[wid] = k2;
    __syncthreads();
    unsigned long long w = swin[0];
#pragma unroll
    for (int q = 1; q < 4; q++) if (swin[q] > w) w = swin[q];
    __syncthreads();
    if (w == 0ull) break;
    if (key == w) key = 0ull;  // unique owner (i unique per gt) consumes
    if (tid == 0) {
      unsigned iwin = 0xFFFFFFFFu - (unsigned)(w & 0xFFFFFFFFull);
      atomicMax(&point_key[iwin], area_key);
    }
  }
}

// Per point: resolve key -> (ind, label), count matches, write bt/at.
__global__ void k_assign(const unsigned long long* __restrict__ point_key,
                         const float* __restrict__ pts,
                         const float* __restrict__ spp,
                         const float* __restrict__ gtb,
                         const int* __restrict__ gtl,
                         int* __restrict__ counts,
                         float* __restrict__ out_labels,
                         float* __restrict__ out_bt,
                         float* __restrict__ out_at,
                         int N, int G) {
  int i = blockIdx.x * blockDim.x + threadIdx.x;
  if (i >= N) return;
  unsigned long long key = point_key[i];
  int g = 0;
  if (key != 0ull) {
    g = (G - 1) - (int)(key & 0xFFFFFFFFull);
    out_labels[i] = (float)gtl[g];
    atomicAdd(&counts[g], 1);
  } else {
    out_labels[i] = BG_F;  // argmax of all-zero row -> ind 0, label BG
  }
  float gx = gtb[g * 5 + 0], gy = gtb[g * 5 + 1];
  float gw = gtb[g * 5 + 2], gh = gtb[g * 5 + 3], ga = gtb[g * 5 + 4];
  float cg = cosf(ga), sg = sinf(ga);
  float px = pts[i * 2 + 0] - gx, py = pts[i * 2 + 1] - gy;
  float ox = px * cg + py * sg, oy = -px * sg + py * cg;
  float st = spp[i];
  out_bt[i * 4 + 0] = (gw * 0.5f + ox) / st;
  out_bt[i * 4 + 1] = (gh * 0.5f + oy) / st;
  out_bt[i * 4 + 2] = (gw * 0.5f - ox) / st;
  out_bt[i * 4 + 3] = (gh * 0.5f - oy) / st;
  out_at[i] = ga;
}

// One wave, lane = gt. Unmatched gts claim their anchor point. Exact
// last-writer-wins (ascending g) on duplicate anchors via shfl resolution:
// lane g yields if any higher unmatched lane has the same anchor.
__global__ void k_fix(const int* __restrict__ counts,
                      const unsigned long long* __restrict__ cent_key,
                      const float* __restrict__ pts,
                      const float* __restrict__ spp,
                      const float* __restrict__ gtb,
                      const int* __restrict__ gtl,
                      float* __restrict__ out_labels,
                      float* __restrict__ out_bt,
                      float* __restrict__ out_at,
                      int G) {
  int g = threadIdx.x;  // blockDim = 64, G <= 64
  bool active = (g < G) && (counts[g] == 0);
  unsigned anchor = 0xFFFFFFFFu;
  if (active) anchor = 0xFFFFFFFFu - (unsigned)(cent_key[g] & 0xFFFFFFFFull);
  unsigned long long act = __ballot(active);
  bool winner = active;
  for (int o = 0; o < 64; o++) {
    unsigned oa = __shfl(anchor, o, 64);
    if (active && o > g && ((act >> o) & 1ull) && oa == anchor) winner = false;
  }
  if (winner) {
    unsigned i = anchor;
    out_labels[i] = (float)gtl[g];
    float gx = gtb[g * 5 + 0], gy = gtb[g * 5 + 1];
    float gw = gtb[g * 5 + 2], gh = gtb[g * 5 + 3], ga = gtb[g * 5 + 4];
    float cg = cosf(ga), sg = sinf(ga);
    float px = pts[i * 2 + 0] - gx, py = pts[i * 2 + 1] - gy;
    float ox = px * cg + py * sg, oy = -px * sg + py * cg;
    float st = spp[i];
    out_bt[i * 4 + 0] = (gw * 0.5f + ox) / st;
    out_bt[i * 4 + 1] = (gh * 0.5f + oy) / st;
    out_bt[i * 4 + 2] = (gw * 0.5f - ox) / st;
    out_bt[i * 4 + 3] = (gh * 0.5f - oy) / st;
    out_at[i] = ga;
  }
}

extern "C" void kernel_launch(void* const* d_in, const int* in_sizes, int n_in,
                              void* d_out, int out_size, void* d_ws, size_t ws_size,
                              hipStream_t stream) {
  const float* pts   = (const float*)d_in[0];
  const float* rr    = (const float*)d_in[1];
  const float* spp   = (const float*)d_in[2];
  const float* gtb   = (const float*)d_in[3];
  const int*   gtl   = (const int*)d_in[4];
  const float* preds = (const float*)d_in[5];
  const float* probs = (const float*)d_in[6];
  int N = in_sizes[0] / 2;
  int G = in_sizes[3] / 5;

  float* out = (float*)d_out;
  float* out_labels = out;                   // N
  float* out_bt     = out + N;               // N*4
  float* out_at     = out + 5 * (size_t)N;   // N

  // workspace: [point_key N u64 | counts G i32]  <- memset 0
  //            [cent_key G u64 (plain-stored by k_all)]
  unsigned long long* point_key = (unsigned long long*)d_ws;       // N
  int* counts = (int*)(point_key + N);                             // G
  unsigned long long* cent_key =
      (unsigned long long*)(counts + ((G + 1) & ~1));              // G

  size_t zbytes = (size_t)N * 8 + (size_t)G * 4;
  hipMemsetAsync(d_ws, 0, zbytes, stream);

  const int thr = 256;
  hipLaunchKernelGGL(k_all, dim3(G), dim3(thr), 0, stream,
                     pts, rr, spp, gtb, gtl, preds, probs,
                     cent_key, point_key, N, G);
  hipLaunchKernelGGL(k_assign, dim3((N + thr - 1) / thr), dim3(thr), 0, stream,
                     point_key, pts, spp, gtb, gtl, counts,
                     out_labels, out_bt, out_at, N, G);
  hipLaunchKernelGGL(k_fix, dim3(1), dim3(64), 0, stream,
                     counts, cent_key, pts, spp, gtb, gtl,
                     out_labels, out_bt, out_at, G);
}

// Round 6
// 103.168 us; speedup vs baseline: 1.6343x; 1.2677x over previous
//
#include <hip/hip_runtime.h>
#include <math.h>

#define NC 15
#define TOPKK 15
#define BG_F 15.0f
#define MAXC 256

// All-register rotated-box IoU. Mirrors pairwise_riou exactly:
// fixed candidate slots 0..15 = edge intersections (e1*4+e2),
// 16..19 = corners of box1, 20..23 = corners of box2; a validity BITMASK
// replaces boolean arrays; stable repeated min-extraction over angles
// (strict <, lowest slot first) replicates stable jnp.argsort order.
// No runtime array indexing anywhere -> no scratch.
__device__ __forceinline__ float obb_iou_reg(
    float cx1, float cy1, float w1, float h1, float a1,
    float cx2, float cy2, float w2, float h2, float a2) {
  const float dxs[4] = {0.5f, 0.5f, -0.5f, -0.5f};
  const float dys[4] = {-0.5f, 0.5f, 0.5f, -0.5f};
  float c1 = cosf(a1), s1 = sinf(a1), c2 = cosf(a2), s2 = sinf(a2);
  float ax[4], ay[4], bx[4], by[4];
#pragma unroll
  for (int k = 0; k < 4; k++) {
    float dx = dxs[k] * w1, dy = dys[k] * h1;
    ax[k] = cx1 + dx * c1 - dy * s1;
    ay[k] = cy1 + dx * s1 + dy * c1;
    dx = dxs[k] * w2; dy = dys[k] * h2;
    bx[k] = cx2 + dx * c2 - dy * s2;
    by[k] = cy2 + dx * s2 + dy * c2;
  }
  float qx[24], qy[24];
#pragma unroll
  for (int k = 0; k < 24; k++) { qx[k] = 0.f; qy[k] = 0.f; }
  unsigned valid = 0u;
#pragma unroll
  for (int e1 = 0; e1 < 4; e1++) {
    float d1x = ax[(e1 + 1) & 3] - ax[e1], d1y = ay[(e1 + 1) & 3] - ay[e1];
#pragma unroll
    for (int e2 = 0; e2 < 4; e2++) {
      float d2x = bx[(e2 + 1) & 3] - bx[e2], d2y = by[(e2 + 1) & 3] - by[e2];
      float den = d1x * d2y - d1y * d2x;
      float qpx = bx[e2] - ax[e1], qpy = by[e2] - ay[e1];
      float t = (qpx * d2y - qpy * d2x) / den;
      float u = (qpx * d1y - qpy * d1x) / den;
      bool ok = (fabsf(den) > 1e-10f) &&
                (t >= 0.f) && (t <= 1.f) && (u >= 0.f) && (u <= 1.f);
      if (ok) {
        qx[e1 * 4 + e2] = ax[e1] + t * d1x;
        qy[e1 * 4 + e2] = ay[e1] + t * d1y;
        valid |= (1u << (e1 * 4 + e2));
      }
    }
  }
  const float eps = 1e-6f;
#pragma unroll
  for (int k = 0; k < 4; k++) {
    float rx = ax[k] - cx2, ry = ay[k] - cy2;
    float x = rx * c2 + ry * s2, y = -rx * s2 + ry * c2;
    if (fabsf(x) <= w2 * 0.5f + eps && fabsf(y) <= h2 * 0.5f + eps) {
      qx[16 + k] = ax[k]; qy[16 + k] = ay[k];
      valid |= (1u << (16 + k));
    }
  }
#pragma unroll
  for (int k = 0; k < 4; k++) {
    float rx = bx[k] - cx1, ry = by[k] - cy1;
    float x = rx * c1 + ry * s1, y = -rx * s1 + ry * c1;
    if (fabsf(x) <= w1 * 0.5f + eps && fabsf(y) <= h1 * 0.5f + eps) {
      qx[20 + k] = bx[k]; qy[20 + k] = by[k];
      valid |= (1u << (20 + k));
    }
  }
  int cnt = __popc(valid);
  float inter = 0.f;
  if (cnt > 0) {
    float sx = 0.f, sy = 0.f;
#pragma unroll
    for (int k = 0; k < 24; k++) {
      bool v = (valid >> k) & 1u;
      sx += v ? qx[k] : 0.f;
      sy += v ? qy[k] : 0.f;
    }
    float ccx = sx / (float)cnt, ccy = sy / (float)cnt;
    float ang[24];
#pragma unroll
    for (int k = 0; k < 24; k++) {
      float a = atan2f(qy[k] - ccy, qx[k] - ccx);
      ang[k] = ((valid >> k) & 1u) ? a : 1e9f;
    }
    unsigned used = ~valid;  // invalid slots pre-consumed
    float area2 = 0.f;
    float prevx = 0.f, prevy = 0.f, firstx = 0.f, firsty = 0.f;
    for (int s = 0; s < cnt; s++) {
      float ba = 1e30f, bxv = 0.f, byv = 0.f;
      int bk = 0;
#pragma unroll
      for (int k = 0; k < 24; k++) {
        bool avail = !((used >> k) & 1u);
        bool better = avail && (ang[k] < ba);
        if (better) { ba = ang[k]; bxv = qx[k]; byv = qy[k]; bk = k; }
      }
      used |= (1u << bk);
      float vx = bxv - ccx, vy = byv - ccy;
      if (s == 0) { firstx = vx; firsty = vy; }
      else { area2 += prevx * vy - prevy * vx; }
      prevx = vx; prevy = vy;
    }
    area2 += prevx * firsty - prevy * firstx;  // closing edge
    inter = 0.5f * fabsf(area2);
  }
  float areaA = w1 * h1, areaB = w2 * h2;
  return inter / fmaxf(areaA + areaB - inter, 1e-8f);
}

// Wide scan: blk = chunk*G + g (g-blocks of one chunk reuse point data in L1/L2).
// Per-block centerness best -> PLAIN STORE to blk_cent[blk] (no atomics).
// Valid candidates: wave-aggregated leader atomicAdd (only waves containing
// valid points issue one). g==0 blocks zero point_key.
__global__ void k_scan(const float* __restrict__ pts,
                       const float* __restrict__ rr,
                       const float* __restrict__ spp,
                       const float* __restrict__ gtb,
                       int* __restrict__ cand_cnt,
                       int* __restrict__ cand_i,
                       unsigned long long* __restrict__ blk_cent,
                       unsigned long long* __restrict__ point_key,
                       int N, int G) {
  int blk = blockIdx.x;
  int g = blk % G, chunk = blk / G;
  int i = chunk * 256 + threadIdx.x;
  if (g == 0 && i < N) point_key[i] = 0ull;
  float gx = gtb[g * 5 + 0], gy = gtb[g * 5 + 1];
  float gw = gtb[g * 5 + 2], gh = gtb[g * 5 + 3], ga = gtb[g * 5 + 4];
  float cg = cosf(ga), sg = sinf(ga);
  float inv_gw = 2.f / gw, inv_gh = 2.f / gh;
  float hw = gw * 0.5f, hh = gh * 0.5f;

  unsigned long long key = 0ull;
  bool valid = false;
  if (i < N) {
    float2 p = ((const float2*)pts)[i];
    float px = p.x - gx, py = p.y - gy;
    float ox = px * cg + py * sg, oy = -px * sg + py * cg;
    float nx = ox * inv_gw, ny = oy * inv_gh;
    float ctn = fmaxf(1.f - sqrtf((nx * nx + ny * ny + 1e-8f) * 0.5f), 0.f);
    key = ((unsigned long long)__float_as_uint(ctn) << 32) |
          (unsigned long long)(0xFFFFFFFFu - (unsigned)i);
    float l = hw + ox, tt = hh + oy, r = hw - ox, b = hh - oy;
    float minb = fminf(fminf(l, tt), fminf(r, b));
    float maxb = fmaxf(fmaxf(l, tt), fmaxf(r, b));
    float cr = 1.5f * spp[i];
    float2 rv = ((const float2*)rr)[i];
    valid = (minb > 0.f) && (fabsf(ox) < cr) && (fabsf(oy) < cr) &&
            (maxb >= rv.x) && (maxb <= rv.y);
  }
  // block reduce centerness key (max ctn, min i via ~i): wave shfl + LDS
  unsigned long long best = key;
#pragma unroll
  for (int o = 32; o > 0; o >>= 1) {
    unsigned long long other = __shfl_xor(best, o, 64);
    if (other > best) best = other;
  }
  __shared__ unsigned long long swin[4];
  int lane = threadIdx.x & 63, wid = threadIdx.x >> 6;
  if (lane == 0) swin[wid] = best;
  __syncthreads();
  if (threadIdx.x == 0) {
    unsigned long long m = swin[0];
#pragma unroll
    for (int q = 1; q < 4; q++) if (swin[q] > m) m = swin[q];
    blk_cent[blk] = m;
  }
  // wave-aggregated append of valid point indices
  unsigned long long ball = __ballot(valid);
  if (ball) {
    int leader = __ffsll(ball) - 1;
    int base = 0;
    if (lane == leader) base = atomicAdd(&cand_cnt[g], __popcll(ball));
    base = __shfl(base, leader, 64);
    if (valid) {
      int slot = base + __popcll(ball & ((1ull << lane) - 1ull));
      if (slot < MAXC) cand_i[g * MAXC + slot] = i;
    }
  }
}

// One block per gt (small work now): (1) reduce blk_cent over chunks ->
// cent_key[g]; (2) per-candidate cost (softmax + decode + register IoU);
// (3) top-15 block argmax rounds, exact lax.top_k tie rule (value desc,
// index asc); winners atomicMax the per-point area key
// (area_bits<<32)|(G-1-g) -> max area, min g on ties (jnp.argmax rule).
__global__ void k_all(const float* __restrict__ pts,
                      const float* __restrict__ spp,
                      const float* __restrict__ gtb,
                      const int* __restrict__ gtl,
                      const float* __restrict__ preds,
                      const float* __restrict__ probs,
                      const int* __restrict__ cand_cnt,
                      const int* __restrict__ cand_i,
                      const unsigned long long* __restrict__ blk_cent,
                      unsigned long long* __restrict__ cent_key,
                      unsigned long long* __restrict__ point_key,
                      int G, int CH) {
  int g = blockIdx.x;
  int tid = threadIdx.x;
  int lane = tid & 63, wid = tid >> 6;
  float gx = gtb[g * 5 + 0], gy = gtb[g * 5 + 1];
  float gw = gtb[g * 5 + 2], gh = gtb[g * 5 + 3], ga = gtb[g * 5 + 4];
  float cg = cosf(ga), sg = sinf(ga);
  float inv_gw = 2.f / gw, inv_gh = 2.f / gh;
  __shared__ unsigned long long swin[4];

  // reduce per-chunk centerness keys
  unsigned long long best = 0ull;
  for (int c = tid; c < CH; c += 256) {
    unsigned long long e = blk_cent[(size_t)c * G + g];
    if (e > best) best = e;
  }
#pragma unroll
  for (int o = 32; o > 0; o >>= 1) {
    unsigned long long other = __shfl_xor(best, o, 64);
    if (other > best) best = other;
  }
  if (lane == 0) swin[wid] = best;
  __syncthreads();
  if (tid == 0) {
    unsigned long long m = swin[0];
#pragma unroll
    for (int q = 1; q < 4; q++) if (swin[q] > m) m = swin[q];
    cent_key[g] = m;
  }
  __syncthreads();

  int cnt = cand_cnt[g];
  if (cnt > MAXC) cnt = MAXC;

  // heavy phase: cost per candidate
  unsigned long long key = 0ull;
  if (tid < cnt) {
    int i = cand_i[g * MAXC + tid];
    float ptx = pts[i * 2 + 0], pty = pts[i * 2 + 1];
    float px = ptx - gx, py = pty - gy;
    float ox = px * cg + py * sg, oy = -px * sg + py * cg;
    float nx = ox * inv_gw, ny = oy * inv_gh;
    float ctn = fmaxf(1.f - sqrtf((nx * nx + ny * ny + 1e-8f) * 0.5f), 0.f);

    // softmax prob of this gt's label (jax.nn.softmax with max subtraction)
    float pv[NC];
    float m = -1e30f;
#pragma unroll
    for (int k = 0; k < NC; k++) { pv[k] = probs[i * NC + k]; m = fmaxf(m, pv[k]); }
    float ss = 0.f;
#pragma unroll
    for (int k = 0; k < NC; k++) { pv[k] = expf(pv[k] - m); ss += pv[k]; }
    float prob = pv[gtl[g]] / ss;

    // decode det box (mirrors _decode with stride-scaled preds)
    float st = spp[i];
    float d0 = preds[i * 5 + 0] * st, d1 = preds[i * 5 + 1] * st;
    float d2 = preds[i * 5 + 2] * st, d3 = preds[i * 5 + 3] * st;
    float angp = preds[i * 5 + 4];
    float c = cosf(angp), s = sinf(angp);
    float w = d0 + d2, h = d1 + d3;
    float otx = (d2 - d0) * 0.5f, oty = (d3 - d1) * 0.5f;
    float dox = c * otx - s * oty, doy = s * otx + c * oty;
    const float PI = 3.14159265358979323846f;
    float a = fmodf(angp + PI * 0.5f, PI);
    if (a < 0.f) a += PI;
    a -= PI * 0.5f;

    float iou = obb_iou_reg(ptx + dox, pty + doy, w, h, a,
                            gx, gy, gw, gh, ga);
    float cval = 0.2f * ctn + 0.2f * iou + 0.6f * prob;
    key = ((unsigned long long)__float_as_uint(cval) << 32) |
          (unsigned long long)(0xFFFFFFFFu - (unsigned)i);
  }

  float area = gw * gh;
  unsigned long long area_key =
      (((unsigned long long)__float_as_uint(area)) << 32) |
      (unsigned long long)(unsigned)(G - 1 - g);
  int rounds = cnt < TOPKK ? cnt : TOPKK;
  for (int r = 0; r < rounds; r++) {
    unsigned long long k2 = key;
#pragma unroll
    for (int o = 32; o > 0; o >>= 1) {
      unsigned long long other = __shfl_xor(k2, o, 64);
      if (other > k2) k2 = other;
    }
    if (lane == 0) swin[wid] = k2;
    __syncthreads();
    unsigned long long w = swin[0];
#pragma unroll
    for (int q = 1; q < 4; q++) if (swin[q] > w) w = swin[q];
    __syncthreads();
    if (w == 0ull) break;
    if (key == w) key = 0ull;  // unique owner (i unique per gt) consumes
    if (tid == 0) {
      unsigned iwin = 0xFFFFFFFFu - (unsigned)(w & 0xFFFFFFFFull);
      atomicMax(&point_key[iwin], area_key);
    }
  }
}

// Per point: resolve key -> (ind, label), count matches, write bt/at.
__global__ void k_assign(const unsigned long long* __restrict__ point_key,
                         const float* __restrict__ pts,
                         const float* __restrict__ spp,
                         const float* __restrict__ gtb,
                         const int* __restrict__ gtl,
                         int* __restrict__ counts,
                         float* __restrict__ out_labels,
                         float* __restrict__ out_bt,
                         float* __restrict__ out_at,
                         int N, int G) {
  int i = blockIdx.x * blockDim.x + threadIdx.x;
  if (i >= N) return;
  unsigned long long key = point_key[i];
  int g = 0;
  if (key != 0ull) {
    g = (G - 1) - (int)(key & 0xFFFFFFFFull);
    out_labels[i] = (float)gtl[g];
    atomicAdd(&counts[g], 1);
  } else {
    out_labels[i] = BG_F;  // argmax of all-zero row -> ind 0, label BG
  }
  float gx = gtb[g * 5 + 0], gy = gtb[g * 5 + 1];
  float gw = gtb[g * 5 + 2], gh = gtb[g * 5 + 3], ga = gtb[g * 5 + 4];
  float cg = cosf(ga), sg = sinf(ga);
  float px = pts[i * 2 + 0] - gx, py = pts[i * 2 + 1] - gy;
  float ox = px * cg + py * sg, oy = -px * sg + py * cg;
  float st = spp[i];
  out_bt[i * 4 + 0] = (gw * 0.5f + ox) / st;
  out_bt[i * 4 + 1] = (gh * 0.5f + oy) / st;
  out_bt[i * 4 + 2] = (gw * 0.5f - ox) / st;
  out_bt[i * 4 + 3] = (gh * 0.5f - oy) / st;
  out_at[i] = ga;
}

// One wave, lane = gt. Unmatched gts claim their anchor point. Exact
// last-writer-wins (ascending g) on duplicate anchors via shfl resolution:
// lane g yields if any higher unmatched lane has the same anchor.
__global__ void k_fix(const int* __restrict__ counts,
                      const unsigned long long* __restrict__ cent_key,
                      const float* __restrict__ pts,
                      const float* __restrict__ spp,
                      const float* __restrict__ gtb,
                      const int* __restrict__ gtl,
                      float* __restrict__ out_labels,
                      float* __restrict__ out_bt,
                      float* __restrict__ out_at,
                      int G) {
  int g = threadIdx.x;  // blockDim = 64, G <= 64
  bool active = (g < G) && (counts[g] == 0);
  unsigned anchor = 0xFFFFFFFFu;
  if (active) anchor = 0xFFFFFFFFu - (unsigned)(cent_key[g] & 0xFFFFFFFFull);
  unsigned long long act = __ballot(active);
  bool winner = active;
  for (int o = 0; o < 64; o++) {
    unsigned oa = __shfl(anchor, o, 64);
    if (active && o > g && ((act >> o) & 1ull) && oa == anchor) winner = false;
  }
  if (winner) {
    unsigned i = anchor;
    out_labels[i] = (float)gtl[g];
    float gx = gtb[g * 5 + 0], gy = gtb[g * 5 + 1];
    float gw = gtb[g * 5 + 2], gh = gtb[g * 5 + 3], ga = gtb[g * 5 + 4];
    float cg = cosf(ga), sg = sinf(ga);
    float px = pts[i * 2 + 0] - gx, py = pts[i * 2 + 1] - gy;
    float ox = px * cg + py * sg, oy = -px * sg + py * cg;
    float st = spp[i];
    out_bt[i * 4 + 0] = (gw * 0.5f + ox) / st;
    out_bt[i * 4 + 1] = (gh * 0.5f + oy) / st;
    out_bt[i * 4 + 2] = (gw * 0.5f - ox) / st;
    out_bt[i * 4 + 3] = (gh * 0.5f - oy) / st;
    out_at[i] = ga;
  }
}

extern "C" void kernel_launch(void* const* d_in, const int* in_sizes, int n_in,
                              void* d_out, int out_size, void* d_ws, size_t ws_size,
                              hipStream_t stream) {
  const float* pts   = (const float*)d_in[0];
  const float* rr    = (const float*)d_in[1];
  const float* spp   = (const float*)d_in[2];
  const float* gtb   = (const float*)d_in[3];
  const int*   gtl   = (const int*)d_in[4];
  const float* preds = (const float*)d_in[5];
  const float* probs = (const float*)d_in[6];
  int N = in_sizes[0] / 2;
  int G = in_sizes[3] / 5;
  int CH = (N + 255) / 256;  // point chunks

  float* out = (float*)d_out;
  float* out_labels = out;                   // N
  float* out_bt     = out + N;               // N*4
  float* out_at     = out + 5 * (size_t)N;   // N

  // ws: [cand_cnt G | counts G] (memset 0) [cent_key G u64]
  //     [point_key N u64 (zeroed by k_scan g==0)] [blk_cent CH*G u64]
  //     [cand_i G*MAXC i32]
  int* cand_cnt = (int*)d_ws;                                     // G
  int* counts   = cand_cnt + G;                                   // G
  unsigned long long* cent_key  = (unsigned long long*)(counts + G);  // G
  unsigned long long* point_key = cent_key + G;                   // N
  unsigned long long* blk_cent  = point_key + N;                  // CH*G
  int* cand_i = (int*)(blk_cent + (size_t)CH * G);                // G*MAXC

  hipMemsetAsync(d_ws, 0, (size_t)G * 8, stream);

  const int thr = 256;
  hipLaunchKernelGGL(k_scan, dim3(CH * G), dim3(thr), 0, stream,
                     pts, rr, spp, gtb, cand_cnt, cand_i,
                     blk_cent, point_key, N, G);
  hipLaunchKernelGGL(k_all, dim3(G), dim3(thr), 0, stream,
                     pts, spp, gtb, gtl, preds, probs,
                     cand_cnt, cand_i, blk_cent, cent_key, point_key, G, CH);
  hipLaunchKernelGGL(k_assign, dim3((N + thr - 1) / thr), dim3(thr), 0, stream,
                     point_key, pts, spp, gtb, gtl, counts,
                     out_labels, out_bt, out_at, N, G);
  hipLaunchKernelGGL(k_fix, dim3(1), dim3(64), 0, stream,
                     counts, cent_key, pts, spp, gtb, gtl,
                     out_labels, out_bt, out_at, G);
}